// Round 5
// baseline (175.325 us; speedup 1.0000x reference)
//
#include <hip/hip_runtime.h>
#include <hip/hip_fp16.h>
#include <cmath>

typedef _Float16 f16;
typedef __attribute__((ext_vector_type(8))) _Float16 f16x8;
typedef __attribute__((ext_vector_type(4))) _Float16 f16x4;
typedef __attribute__((ext_vector_type(4))) float f32x4;

// async 16B global->LDS (per-lane global addr; LDS dest = base + lane*16)
typedef __attribute__((address_space(3))) unsigned int lds_u32;
typedef const __attribute__((address_space(1))) unsigned int g_u32;
__device__ __forceinline__ void async_copy16(const void* g, void* l) {
    __builtin_amdgcn_global_load_lds((g_u32*)g, (lds_u32*)l, 16, 0, 0);
}

#define EXP2F(x) __builtin_amdgcn_exp2f(x)

// ---------------------------------------------------------------------------
// fused f32 -> f16 cast over 3 segments (x, qkv_w, proj_w), 4 elems/thread
// ---------------------------------------------------------------------------
__global__ void cast3_f32_f16(const float* __restrict__ s0, f16* __restrict__ d0, int n0,
                              const float* __restrict__ s1, f16* __restrict__ d1, int n1,
                              const float* __restrict__ s2, f16* __restrict__ d2, int n2) {
    int i = blockIdx.x * blockDim.x + threadIdx.x;
    const float* s; f16* d; int j;
    if (i < n0)                { s = s0; d = d0; j = i; }
    else if (i < n0 + n1)      { s = s1; d = d1; j = i - n0; }
    else if (i < n0 + n1 + n2) { s = s2; d = d2; j = i - n0 - n1; }
    else return;
    float4 v = ((const float4*)s)[j];
    f16x4 o = { (f16)v.x, (f16)v.y, (f16)v.z, (f16)v.w };
    ((f16x4*)d)[j] = o;
}

__device__ __forceinline__ void store4(f16* p, const f32x4& v) {
    f16x4 o = { (f16)v[0], (f16)v[1], (f16)v[2], (f16)v[3] };
    *(f16x4*)p = o;
}
__device__ __forceinline__ void store4(float* p, const f32x4& v) {
    float4 o = { v[0], v[1], v[2], v[3] };
    *(float4*)p = o;
}

// ---------------------------------------------------------------------------
// MFMA f16 GEMM: out[M,N] = A[M,K] @ W[N,K]^T + bias[N], fp32 accumulate.
// OPERAND-SWAPPED: A-operand = W rows, B-operand = A rows -> C/D has
// col(lane&15)=out ROW, row(q4*4+reg)=out COL => each lane holds 4
// consecutive out columns -> vectorized f16x4/float4 epilogue stores.
// 128x128 tile, BK=32, frag-ready LDS via global_load_lds width=16.
// ---------------------------------------------------------------------------
#define BM 128
#define BN 128
#define BK 32

template <typename OT>
__global__ __launch_bounds__(256) void gemm_f16_nt(
    const f16* __restrict__ A,      // [M,K]
    const f16* __restrict__ W,      // [N,K]
    const float* __restrict__ bias, // [N]
    OT* __restrict__ out,           // [M,N]
    int M, int N, int K)
{
    __shared__ f16 Ash[8 * 512];
    __shared__ f16 Bsh[8 * 512];

    const int tid  = threadIdx.x;
    const int lane = tid & 63;
    const int w    = tid >> 6;
    const int wr   = w >> 1;
    const int wc   = w & 1;
    const int bm   = blockIdx.y * BM;
    const int bn   = blockIdx.x * BN;

    const int lr = lane & 15;
    const int lq = lane >> 4;

    const f16* ga0 = A + (size_t)(bm + (2 * w + 0) * 16 + lr) * K + lq * 8;
    const f16* ga1 = A + (size_t)(bm + (2 * w + 1) * 16 + lr) * K + lq * 8;
    const f16* gb0 = W + (size_t)(bn + (2 * w + 0) * 16 + lr) * K + lq * 8;
    const f16* gb1 = W + (size_t)(bn + (2 * w + 1) * 16 + lr) * K + lq * 8;
    f16* la0 = &Ash[(2 * w + 0) * 512];
    f16* la1 = &Ash[(2 * w + 1) * 512];
    f16* lb0 = &Bsh[(2 * w + 0) * 512];
    f16* lb1 = &Bsh[(2 * w + 1) * 512];

    f32x4 acc[4][4] = {};

    for (int k0 = 0; k0 < K; k0 += BK) {
        __syncthreads();
        async_copy16(ga0 + k0, la0);
        async_copy16(ga1 + k0, la1);
        async_copy16(gb0 + k0, lb0);
        async_copy16(gb1 + k0, lb1);
        __syncthreads();

        f16x8 af[4], bf[4];
#pragma unroll
        for (int mt = 0; mt < 4; ++mt)
            af[mt] = *(const f16x8*)&Ash[(wr * 4 + mt) * 512 + lane * 8];
#pragma unroll
        for (int nt = 0; nt < 4; ++nt)
            bf[nt] = *(const f16x8*)&Bsh[(wc * 4 + nt) * 512 + lane * 8];
        // swapped: A-op = W frag (out-col as m'), B-op = A frag (out-row as n')
#pragma unroll
        for (int mt = 0; mt < 4; ++mt)
#pragma unroll
            for (int nt = 0; nt < 4; ++nt)
                acc[mt][nt] = __builtin_amdgcn_mfma_f32_16x16x32_f16(
                    bf[nt], af[mt], acc[mt][nt], 0, 0, 0);
    }

    // epilogue: lane holds out[row = bm+wr*64+mt*16+lr][col .. col+3],
    // col = bn+wc*64+nt*16+lq*4  -> vector store
#pragma unroll
    for (int mt = 0; mt < 4; ++mt) {
        int row = bm + wr * 64 + mt * 16 + lr;
#pragma unroll
        for (int nt = 0; nt < 4; ++nt) {
            int col = bn + wc * 64 + nt * 16 + lq * 4;
            float4 bv = *(const float4*)(bias + col);
            f32x4 ov = acc[mt][nt];
            ov[0] += bv.x; ov[1] += bv.y; ov[2] += bv.z; ov[3] += bv.w;
            store4(out + (size_t)row * N + col, ov);
        }
    }
}

// ---------------------------------------------------------------------------
// MFMA local attention, window=128, hd=64 (operand-swapped).
// S^T = K·Q^T: lane owns q-row r15 -> row max/sum = in-register + 2 shuffles.
// O^T = V^T·P^T: lane holds 4 consecutive d -> f16x4 stores.
// Q prescaled by 0.125*log2(e); softmax in exp2 domain.
// Swizzles: Vt (c,d) at d*64+(((c>>3)^(d>>3)^d)&7)*8+(c&7);
//           Ps frag slot ls -> ls^((ls>>3)&7).
// LDS = 8+8+8 = 24 KB.
// ---------------------------------------------------------------------------
#define WINDOW_SZ 128

__global__ __launch_bounds__(256) void local_attn_mfma(
    const f16* __restrict__ qkv,  // [N, 2304] f16: [q(12*64)|k|v]
    f16* __restrict__ out,        // [N, 768] f16
    int N)
{
    const int C  = 768;
    const int C3 = 2304;
    __shared__ f16 Ks[8 * 512];   // K A-frag segs (nt, ks)
    __shared__ f16 Vt[4096];      // swizzled V^T
    __shared__ f16 Ps[8 * 512];   // P B-frag segs (w, cs)

    const int tid  = threadIdx.x;
    const int lane = tid & 63;
    const int w    = tid >> 6;
    const int r15  = lane & 15;
    const int q4   = lane >> 4;
    const int ntiles = N >> 6;
    const int h  = blockIdx.x / ntiles;
    const int i0 = (blockIdx.x % ntiles) << 6;
    const int qoff = h * 64;
    const int koff = 768 + h * 64;
    const int voff = 1536 + h * 64;

    // Q B-frags (loop-invariant), prescaled by 0.125*log2(e)
    f16x8 qf[2];
    {
        const f16* qrow = qkv + (size_t)(i0 + w * 16 + r15) * C3 + qoff + q4 * 8;
        qf[0] = *(const f16x8*)(qrow);
        qf[1] = *(const f16x8*)(qrow + 32);
        const f16 qs = (f16)0.18033688f;
#pragma unroll
        for (int j = 0; j < 8; ++j) { qf[0][j] *= qs; qf[1][j] *= qs; }
    }

    const int vc0 = tid >> 3;
    const int vd0 = (tid & 7) * 8;
    const int va  = vd0 >> 3;

    f32x4 o[4] = {};
    float m_l = -1.0e30f, l_l = 0.f;

    for (int ch = 0; ch < 5; ++ch) {
        int jbase = i0 - 128 + ch * 64;
        if (jbase < 0 || jbase >= N) continue;
        bool need_mask = (ch == 0) || (ch == 4);

        __syncthreads();   // prior chunk's Ks/Vt reads done
        {
            const f16* kr = qkv + (size_t)(jbase + w * 16 + r15) * C3 + koff + q4 * 8;
            async_copy16(kr,      &Ks[(w * 2 + 0) * 512]);
            async_copy16(kr + 32, &Ks[(w * 2 + 1) * 512]);
        }
#pragma unroll
        for (int rep = 0; rep < 2; ++rep) {
            int c = vc0 + rep * 32;
            f16x8 v = *(const f16x8*)(qkv + (size_t)(jbase + c) * C3 + voff + vd0);
            int cc = c >> 3, c7 = c & 7;
#pragma unroll
            for (int j = 0; j < 8; ++j) {
                int x = (cc ^ va ^ j) & 7;
                Vt[(vd0 + j) * 64 + x * 8 + c7] = v[j];
            }
        }
        __syncthreads();

        // S^T = K @ Q^T : s[nt][r] = score(q=r15, key=nt*16+q4*4+r)
        f32x4 s[4] = {};
#pragma unroll
        for (int ks = 0; ks < 2; ++ks)
#pragma unroll
            for (int nt = 0; nt < 4; ++nt) {
                f16x8 kf = *(const f16x8*)&Ks[(nt * 2 + ks) * 512 + lane * 8];
                s[nt] = __builtin_amdgcn_mfma_f32_16x16x32_f16(kf, qf[ks], s[nt], 0, 0, 0);
            }

        if (need_mask) {
            int qg = i0 + w * 16 + r15;
#pragma unroll
            for (int nt = 0; nt < 4; ++nt)
#pragma unroll
                for (int r = 0; r < 4; ++r) {
                    int dist = qg - (jbase + nt * 16 + q4 * 4 + r);
                    if (dist < 0) dist = -dist;
                    if (dist > WINDOW_SZ) s[nt][r] = -3.0e38f;
                }
        }

        // online softmax (exp2 domain), row = this lane's q-row
        float rmax = -3.0e38f;
#pragma unroll
        for (int nt = 0; nt < 4; ++nt)
#pragma unroll
            for (int r = 0; r < 4; ++r) rmax = fmaxf(rmax, s[nt][r]);
        rmax = fmaxf(rmax, __shfl_xor(rmax, 16));
        rmax = fmaxf(rmax, __shfl_xor(rmax, 32));
        float mn = fmaxf(m_l, rmax);
        float al = EXP2F(m_l - mn);
        m_l = mn;
        float rs = 0.f;
#pragma unroll
        for (int nt = 0; nt < 4; ++nt)
#pragma unroll
            for (int r = 0; r < 4; ++r) {
                float p = EXP2F(s[nt][r] - mn);
                s[nt][r] = p;
                rs += p;
            }
        rs += __shfl_xor(rs, 16);
        rs += __shfl_xor(rs, 32);
        l_l = l_l * al + rs;
#pragma unroll
        for (int nd = 0; nd < 4; ++nd)
#pragma unroll
            for (int r = 0; r < 4; ++r) o[nd][r] *= al;

        // P -> Ps in B-frag layout (swizzled); per-wave buffer, no barrier
#pragma unroll
        for (int nt = 0; nt < 4; ++nt)
#pragma unroll
            for (int r = 0; r < 4; ++r) {
                int c  = nt * 16 + q4 * 4 + r;     // key index 0..63
                int cs = c >> 5;
                int c5 = c & 31;
                int ls = (c5 >> 3) * 16 + r15;
                int lss = ls ^ ((ls >> 3) & 7);
                Ps[(w * 2 + cs) * 512 + lss * 8 + (c5 & 7)] = (f16)s[nt][r];
            }

        // O^T += V^T @ P^T
        int lssr = lane ^ ((lane >> 3) & 7);
#pragma unroll
        for (int cs = 0; cs < 2; ++cs) {
            f16x8 pf = *(const f16x8*)&Ps[(w * 2 + cs) * 512 + lssr * 8];
#pragma unroll
            for (int nd = 0; nd < 4; ++nd) {
                int d = nd * 16 + r15;
                int x = ((cs * 4 + q4) ^ (d >> 3) ^ d) & 7;
                f16x8 vf = *(const f16x8*)&Vt[d * 64 + x * 8];
                o[nd] = __builtin_amdgcn_mfma_f32_16x16x32_f16(vf, pf, o[nd], 0, 0, 0);
            }
        }
    }

    // epilogue: lane holds q-row r15, d = nd*16 + q4*4 + (0..3) -> f16x4 stores
    float inv = 1.0f / l_l;
    int row = i0 + w * 16 + r15;
#pragma unroll
    for (int nd = 0; nd < 4; ++nd) {
        f16x4 ov = { (f16)(o[nd][0] * inv), (f16)(o[nd][1] * inv),
                     (f16)(o[nd][2] * inv), (f16)(o[nd][3] * inv) };
        *(f16x4*)(out + (size_t)row * C + qoff + nd * 16 + q4 * 4) = ov;
    }
}

// ---------------------------------------------------------------------------
extern "C" void kernel_launch(void* const* d_in, const int* in_sizes, int n_in,
                              void* d_out, int out_size, void* d_ws, size_t ws_size,
                              hipStream_t stream) {
    (void)n_in; (void)out_size; (void)ws_size;
    const float* x      = (const float*)d_in[0];
    const float* qkv_w  = (const float*)d_in[1];
    const float* qkv_b  = (const float*)d_in[2];
    const float* proj_w = (const float*)d_in[3];
    const float* proj_b = (const float*)d_in[4];
    float* outp = (float*)d_out;

    const int C    = in_sizes[2] / 3;     // 768
    const int Nseq = in_sizes[0] / C;     // 4096
    const int C3   = 3 * C;               // 2304

    char* ws = (char*)d_ws;
    f16* qkv_h = (f16*)ws;   ws += (size_t)Nseq * C3 * 2;   // 18.9 MB
    f16* xh    = (f16*)ws;   ws += (size_t)Nseq * C * 2;    // 6.3 MB (reused as attn_h)
    f16* wh_q  = (f16*)ws;   ws += (size_t)C3 * C * 2;      // 3.5 MB
    f16* wh_p  = (f16*)ws;                                   // 1.2 MB
    f16* attn_h = xh;   // alias: xh dead after GEMM1

    dim3 blk(256);
    {
        int n0 = Nseq * C / 4, n1 = C3 * C / 4, n2 = C * C / 4;
        int tot = n0 + n1 + n2;
        cast3_f32_f16<<<dim3((tot + 255) / 256), blk, 0, stream>>>(
            x, xh, n0, qkv_w, wh_q, n1, proj_w, wh_p, n2);
    }
    // qkv (f16) = x @ qkv_w^T + qkv_b
    gemm_f16_nt<f16><<<dim3(C3 / BN, Nseq / BM), blk, 0, stream>>>(
        xh, wh_q, qkv_b, qkv_h, Nseq, C3, C);
    // banded attention -> f16
    local_attn_mfma<<<dim3((C / 64) * (Nseq / 64)), blk, 0, stream>>>(
        qkv_h, attn_h, Nseq);
    // out (f32) = attn @ proj_w^T + proj_b
    gemm_f16_nt<float><<<dim3(C / BN, Nseq / BM), blk, 0, stream>>>(
        attn_h, wh_p, proj_b, outp, Nseq, C, C);
}

// Round 6
// 163.114 us; speedup vs baseline: 1.0749x; 1.0749x over previous
//
#include <hip/hip_runtime.h>
#include <hip/hip_fp16.h>
#include <cmath>

typedef _Float16 f16;
typedef __attribute__((ext_vector_type(8))) _Float16 f16x8;
typedef __attribute__((ext_vector_type(4))) _Float16 f16x4;
typedef __attribute__((ext_vector_type(4))) float f32x4;

// async 16B global->LDS (per-lane global addr; LDS dest = base + lane*16)
typedef __attribute__((address_space(3))) unsigned int lds_u32;
typedef const __attribute__((address_space(1))) unsigned int g_u32;
__device__ __forceinline__ void async_copy16(const void* g, void* l) {
    __builtin_amdgcn_global_load_lds((g_u32*)g, (lds_u32*)l, 16, 0, 0);
}

#define EXP2F(x) __builtin_amdgcn_exp2f(x)

// ---------------------------------------------------------------------------
// fused f32 -> f16 cast over 3 segments (x, qkv_w, proj_w), 4 elems/thread
// ---------------------------------------------------------------------------
__global__ void cast3_f32_f16(const float* __restrict__ s0, f16* __restrict__ d0, int n0,
                              const float* __restrict__ s1, f16* __restrict__ d1, int n1,
                              const float* __restrict__ s2, f16* __restrict__ d2, int n2) {
    int i = blockIdx.x * blockDim.x + threadIdx.x;
    const float* s; f16* d; int j;
    if (i < n0)                { s = s0; d = d0; j = i; }
    else if (i < n0 + n1)      { s = s1; d = d1; j = i - n0; }
    else if (i < n0 + n1 + n2) { s = s2; d = d2; j = i - n0 - n1; }
    else return;
    float4 v = ((const float4*)s)[j];
    f16x4 o = { (f16)v.x, (f16)v.y, (f16)v.z, (f16)v.w };
    ((f16x4*)d)[j] = o;
}

__device__ __forceinline__ void store4(f16* p, const f32x4& v) {
    f16x4 o = { (f16)v[0], (f16)v[1], (f16)v[2], (f16)v[3] };
    *(f16x4*)p = o;
}
__device__ __forceinline__ void store4(float* p, const f32x4& v) {
    float4 o = { v[0], v[1], v[2], v[3] };
    *(float4*)p = o;
}

// ---------------------------------------------------------------------------
// MFMA f16 GEMM, double-buffered: out[M,N] = A[M,K] @ W[N,K]^T + bias[N].
// Tile 64 x BN_T, BK=32, 4 waves. Wave w: stages A-chunk w + B-chunks
// w*NT..w*NT+NT-1 (NT = BN_T/64 col-tiles per wave); computes all 4 row-tiles
// x its NT col-tiles. Double-buffered LDS: iter k prefetches tile k+1 via
// global_load_lds, computes from buf[k&1], ONE barrier per iter (its vmcnt
// drain lands after the MFMA phase; 4+ blocks/CU hide the residual).
// Operand-swapped MFMA: lane&15 = out row, (lane>>4)*4+reg = out col
// -> vectorized 4-wide epilogue stores.
// ---------------------------------------------------------------------------
template <int BN_T, typename OT>
__global__ __launch_bounds__(256) void gemm_f16_nt_db(
    const f16* __restrict__ A,      // [M,K]
    const f16* __restrict__ W,      // [N,K]
    const float* __restrict__ bias, // [N]
    OT* __restrict__ out,           // [M,N]
    int M, int N, int K)
{
    constexpr int NCH = BN_T / 16;   // B chunks per tile (8 or 4)
    constexpr int NT  = BN_T / 64;   // col-tiles per wave (2 or 1)
    __shared__ f16 Ash[2][4 * 512];
    __shared__ f16 Bsh[2][NCH * 512];

    const int tid  = threadIdx.x;
    const int lane = tid & 63;
    const int w    = tid >> 6;
    const int lr   = lane & 15;
    const int lq   = lane >> 4;
    const int bm   = blockIdx.y * 64;
    const int bn   = blockIdx.x * BN_T;

    const f16* gA = A + (size_t)(bm + w * 16 + lr) * K + lq * 8;
    const f16* gB[NT];
#pragma unroll
    for (int t = 0; t < NT; ++t)
        gB[t] = W + (size_t)(bn + (w * NT + t) * 16 + lr) * K + lq * 8;

    f32x4 acc[4][NT] = {};

    // prologue: stage tile 0 into buf 0
    async_copy16(gA, &Ash[0][w * 512]);
#pragma unroll
    for (int t = 0; t < NT; ++t)
        async_copy16(gB[t], &Bsh[0][(w * NT + t) * 512]);
    __syncthreads();   // vmcnt drain -> buf0 ready

    const int nk = K >> 5;
    for (int k = 0; k < nk; ++k) {
        const int cur = k & 1;
        if (k + 1 < nk) {
            int ko = (k + 1) << 5;
            async_copy16(gA + ko, &Ash[cur ^ 1][w * 512]);
#pragma unroll
            for (int t = 0; t < NT; ++t)
                async_copy16(gB[t] + ko, &Bsh[cur ^ 1][(w * NT + t) * 512]);
        }
        f16x8 af[4], bf[NT];
#pragma unroll
        for (int mt = 0; mt < 4; ++mt)
            af[mt] = *(const f16x8*)&Ash[cur][mt * 512 + lane * 8];
#pragma unroll
        for (int nt = 0; nt < NT; ++nt)
            bf[nt] = *(const f16x8*)&Bsh[cur][(w * NT + nt) * 512 + lane * 8];
#pragma unroll
        for (int mt = 0; mt < 4; ++mt)
#pragma unroll
            for (int nt = 0; nt < NT; ++nt)
                acc[mt][nt] = __builtin_amdgcn_mfma_f32_16x16x32_f16(
                    bf[nt], af[mt], acc[mt][nt], 0, 0, 0);
        __syncthreads();  // reads of buf[cur] done + prefetch into buf[cur^1] drained
    }

    // epilogue: lane holds out[bm+mt*16+lr][col..col+3], col = bn+(w*NT+nt)*16+lq*4
#pragma unroll
    for (int mt = 0; mt < 4; ++mt) {
        int row = bm + mt * 16 + lr;
#pragma unroll
        for (int nt = 0; nt < NT; ++nt) {
            int col = bn + (w * NT + nt) * 16 + lq * 4;
            float4 bv = *(const float4*)(bias + col);
            f32x4 ov = acc[mt][nt];
            ov[0] += bv.x; ov[1] += bv.y; ov[2] += bv.z; ov[3] += bv.w;
            store4(out + (size_t)row * N + col, ov);
        }
    }
}

// ---------------------------------------------------------------------------
// MFMA local attention, window=128, hd=64 (operand-swapped, unchanged R5).
// ---------------------------------------------------------------------------
#define WINDOW_SZ 128

__global__ __launch_bounds__(256) void local_attn_mfma(
    const f16* __restrict__ qkv,  // [N, 2304] f16: [q(12*64)|k|v]
    f16* __restrict__ out,        // [N, 768] f16
    int N)
{
    const int C  = 768;
    const int C3 = 2304;
    __shared__ f16 Ks[8 * 512];   // K A-frag segs (nt, ks)
    __shared__ f16 Vt[4096];      // swizzled V^T
    __shared__ f16 Ps[8 * 512];   // P B-frag segs (w, cs)

    const int tid  = threadIdx.x;
    const int lane = tid & 63;
    const int w    = tid >> 6;
    const int r15  = lane & 15;
    const int q4   = lane >> 4;
    const int ntiles = N >> 6;
    const int h  = blockIdx.x / ntiles;
    const int i0 = (blockIdx.x % ntiles) << 6;
    const int qoff = h * 64;
    const int koff = 768 + h * 64;
    const int voff = 1536 + h * 64;

    // Q B-frags (loop-invariant), prescaled by 0.125*log2(e)
    f16x8 qf[2];
    {
        const f16* qrow = qkv + (size_t)(i0 + w * 16 + r15) * C3 + qoff + q4 * 8;
        qf[0] = *(const f16x8*)(qrow);
        qf[1] = *(const f16x8*)(qrow + 32);
        const f16 qs = (f16)0.18033688f;
#pragma unroll
        for (int j = 0; j < 8; ++j) { qf[0][j] *= qs; qf[1][j] *= qs; }
    }

    const int vc0 = tid >> 3;
    const int vd0 = (tid & 7) * 8;
    const int va  = vd0 >> 3;

    f32x4 o[4] = {};
    float m_l = -1.0e30f, l_l = 0.f;

    for (int ch = 0; ch < 5; ++ch) {
        int jbase = i0 - 128 + ch * 64;
        if (jbase < 0 || jbase >= N) continue;
        bool need_mask = (ch == 0) || (ch == 4);

        __syncthreads();   // prior chunk's Ks/Vt reads done
        {
            const f16* kr = qkv + (size_t)(jbase + w * 16 + r15) * C3 + koff + q4 * 8;
            async_copy16(kr,      &Ks[(w * 2 + 0) * 512]);
            async_copy16(kr + 32, &Ks[(w * 2 + 1) * 512]);
        }
#pragma unroll
        for (int rep = 0; rep < 2; ++rep) {
            int c = vc0 + rep * 32;
            f16x8 v = *(const f16x8*)(qkv + (size_t)(jbase + c) * C3 + voff + vd0);
            int cc = c >> 3, c7 = c & 7;
#pragma unroll
            for (int j = 0; j < 8; ++j) {
                int x = (cc ^ va ^ j) & 7;
                Vt[(vd0 + j) * 64 + x * 8 + c7] = v[j];
            }
        }
        __syncthreads();

        // S^T = K @ Q^T : s[nt][r] = score(q=r15, key=nt*16+q4*4+r)
        f32x4 s[4] = {};
#pragma unroll
        for (int ks = 0; ks < 2; ++ks)
#pragma unroll
            for (int nt = 0; nt < 4; ++nt) {
                f16x8 kf = *(const f16x8*)&Ks[(nt * 2 + ks) * 512 + lane * 8];
                s[nt] = __builtin_amdgcn_mfma_f32_16x16x32_f16(kf, qf[ks], s[nt], 0, 0, 0);
            }

        if (need_mask) {
            int qg = i0 + w * 16 + r15;
#pragma unroll
            for (int nt = 0; nt < 4; ++nt)
#pragma unroll
                for (int r = 0; r < 4; ++r) {
                    int dist = qg - (jbase + nt * 16 + q4 * 4 + r);
                    if (dist < 0) dist = -dist;
                    if (dist > WINDOW_SZ) s[nt][r] = -3.0e38f;
                }
        }

        // online softmax (exp2 domain), row = this lane's q-row
        float rmax = -3.0e38f;
#pragma unroll
        for (int nt = 0; nt < 4; ++nt)
#pragma unroll
            for (int r = 0; r < 4; ++r) rmax = fmaxf(rmax, s[nt][r]);
        rmax = fmaxf(rmax, __shfl_xor(rmax, 16));
        rmax = fmaxf(rmax, __shfl_xor(rmax, 32));
        float mn = fmaxf(m_l, rmax);
        float al = EXP2F(m_l - mn);
        m_l = mn;
        float rs = 0.f;
#pragma unroll
        for (int nt = 0; nt < 4; ++nt)
#pragma unroll
            for (int r = 0; r < 4; ++r) {
                float p = EXP2F(s[nt][r] - mn);
                s[nt][r] = p;
                rs += p;
            }
        rs += __shfl_xor(rs, 16);
        rs += __shfl_xor(rs, 32);
        l_l = l_l * al + rs;
#pragma unroll
        for (int nd = 0; nd < 4; ++nd)
#pragma unroll
            for (int r = 0; r < 4; ++r) o[nd][r] *= al;

        // P -> Ps in B-frag layout (swizzled); per-wave buffer, no barrier
#pragma unroll
        for (int nt = 0; nt < 4; ++nt)
#pragma unroll
            for (int r = 0; r < 4; ++r) {
                int c  = nt * 16 + q4 * 4 + r;     // key index 0..63
                int cs = c >> 5;
                int c5 = c & 31;
                int ls = (c5 >> 3) * 16 + r15;
                int lss = ls ^ ((ls >> 3) & 7);
                Ps[(w * 2 + cs) * 512 + lss * 8 + (c5 & 7)] = (f16)s[nt][r];
            }

        // O^T += V^T @ P^T
        int lssr = lane ^ ((lane >> 3) & 7);
#pragma unroll
        for (int cs = 0; cs < 2; ++cs) {
            f16x8 pf = *(const f16x8*)&Ps[(w * 2 + cs) * 512 + lssr * 8];
#pragma unroll
            for (int nd = 0; nd < 4; ++nd) {
                int d = nd * 16 + r15;
                int x = ((cs * 4 + q4) ^ (d >> 3) ^ d) & 7;
                f16x8 vf = *(const f16x8*)&Vt[d * 64 + x * 8];
                o[nd] = __builtin_amdgcn_mfma_f32_16x16x32_f16(vf, pf, o[nd], 0, 0, 0);
            }
        }
    }

    // epilogue: lane holds q-row r15, d = nd*16 + q4*4 + (0..3) -> f16x4 stores
    float inv = 1.0f / l_l;
    int row = i0 + w * 16 + r15;
#pragma unroll
    for (int nd = 0; nd < 4; ++nd) {
        f16x4 ov = { (f16)(o[nd][0] * inv), (f16)(o[nd][1] * inv),
                     (f16)(o[nd][2] * inv), (f16)(o[nd][3] * inv) };
        *(f16x4*)(out + (size_t)row * C + qoff + nd * 16 + q4 * 4) = ov;
    }
}

// ---------------------------------------------------------------------------
extern "C" void kernel_launch(void* const* d_in, const int* in_sizes, int n_in,
                              void* d_out, int out_size, void* d_ws, size_t ws_size,
                              hipStream_t stream) {
    (void)n_in; (void)out_size; (void)ws_size;
    const float* x      = (const float*)d_in[0];
    const float* qkv_w  = (const float*)d_in[1];
    const float* qkv_b  = (const float*)d_in[2];
    const float* proj_w = (const float*)d_in[3];
    const float* proj_b = (const float*)d_in[4];
    float* outp = (float*)d_out;

    const int C    = in_sizes[2] / 3;     // 768
    const int Nseq = in_sizes[0] / C;     // 4096
    const int C3   = 3 * C;               // 2304

    char* ws = (char*)d_ws;
    f16* qkv_h = (f16*)ws;   ws += (size_t)Nseq * C3 * 2;   // 18.9 MB
    f16* xh    = (f16*)ws;   ws += (size_t)Nseq * C * 2;    // 6.3 MB (reused as attn_h)
    f16* wh_q  = (f16*)ws;   ws += (size_t)C3 * C * 2;      // 3.5 MB
    f16* wh_p  = (f16*)ws;                                   // 1.2 MB
    f16* attn_h = xh;   // alias: xh dead after GEMM1

    dim3 blk(256);
    {
        int n0 = Nseq * C / 4, n1 = C3 * C / 4, n2 = C * C / 4;
        int tot = n0 + n1 + n2;
        cast3_f32_f16<<<dim3((tot + 255) / 256), blk, 0, stream>>>(
            x, xh, n0, qkv_w, wh_q, n1, proj_w, wh_p, n2);
    }
    // qkv (f16) = x @ qkv_w^T + qkv_b   (tile 64x128 -> 1152 blocks)
    gemm_f16_nt_db<128, f16><<<dim3(C3 / 128, Nseq / 64), blk, 0, stream>>>(
        xh, wh_q, qkv_b, qkv_h, Nseq, C3, C);
    // banded attention -> f16
    local_attn_mfma<<<dim3((C / 64) * (Nseq / 64)), blk, 0, stream>>>(
        qkv_h, attn_h, Nseq);
    // out (f32) = attn @ proj_w^T + proj_b   (tile 64x64 -> 768 blocks)
    gemm_f16_nt_db<64, float><<<dim3(C / 64, Nseq / 64), blk, 0, stream>>>(
        attn_h, wh_p, proj_b, outp, Nseq, C, C);
}